// Round 4
// baseline (344.683 us; speedup 1.0000x reference)
//
#include <hip/hip_runtime.h>
#include <cstddef>

#define NSTATE 1280
#define TCACHE 448
#define NBATCH 128
#define NHEAD  20
#define HDIM   64
#define NT     8
#define RPC    (TCACHE / NT)   // 56 rows per chunk

typedef float f4 __attribute__((ext_vector_type(4)));
typedef float f32x4 __attribute__((ext_vector_type(4)));
typedef short bf16x8 __attribute__((ext_vector_type(8)));
typedef unsigned short u16;

__device__ __forceinline__ u16 f2bf(float f) {
    unsigned u = __builtin_bit_cast(unsigned, f);
    u += 0x7fff + ((u >> 16) & 1);          // RTN-even (finite inputs)
    return (u16)(u >> 16);
}

// ---------------------------------------------------------------------------
// Pre-pass: convert W's to bf16 TRANSPOSED WT[mat][n][k]; convert x to bf16.
// grid (20, 20, 5): z<4 -> 64x64 tile of W_z (x=k-tile, y=n-tile);
// z==4 -> x convert (x=k-tile, y=m-tile<2).
// ---------------------------------------------------------------------------
__global__ void __launch_bounds__(256) cvt_kernel(
    const float* __restrict__ Wq, const float* __restrict__ Wk,
    const float* __restrict__ Wv, const float* __restrict__ Wo,
    const float* __restrict__ x, u16* __restrict__ WT, u16* __restrict__ xbf)
{
    const int z = blockIdx.z;
    const int t = threadIdx.x;
    const int r = t >> 2;            // 0..63
    const int c0 = (t & 3) << 4;     // 0,16,32,48
    if (z < 4) {
        const float* src = (z == 0) ? Wq : (z == 1) ? Wk : (z == 2) ? Wv : Wo;
        u16* dst = WT + (size_t)z * NSTATE * NSTATE;
        const int k0 = blockIdx.x * 64, n0 = blockIdx.y * 64;
        __shared__ u16 tile[64][65];   // [n][k]
        #pragma unroll
        for (int j = 0; j < 16; j += 4) {
            float4 v = *(const float4*)(src + (size_t)(k0 + r) * NSTATE + n0 + c0 + j);
            tile[c0 + j + 0][r] = f2bf(v.x);
            tile[c0 + j + 1][r] = f2bf(v.y);
            tile[c0 + j + 2][r] = f2bf(v.z);
            tile[c0 + j + 3][r] = f2bf(v.w);
        }
        __syncthreads();
        u16* o = dst + (size_t)(n0 + r) * NSTATE + k0 + c0;
        #pragma unroll
        for (int j = 0; j < 16; ++j) o[j] = tile[r][c0 + j];
    } else {
        if (blockIdx.y >= 2) return;
        const int k0 = blockIdx.x * 64, m0 = blockIdx.y * 64;
        u16* o = xbf + (size_t)(m0 + r) * NSTATE + k0 + c0;
        #pragma unroll
        for (int j = 0; j < 16; j += 4) {
            float4 v = *(const float4*)(x + (size_t)(m0 + r) * NSTATE + k0 + c0 + j);
            o[j + 0] = f2bf(v.x); o[j + 1] = f2bf(v.y);
            o[j + 2] = f2bf(v.z); o[j + 3] = f2bf(v.w);
        }
    }
}

// ---------------------------------------------------------------------------
// MFMA GEMM body: C[128][1280-slice] = A_bf16[128][1280] @ WT_bf16[n][k]^T.
// BM=128 (all M), BN=64, 4 waves; wave w owns n-slice w*16. No LDS.
// A-frag: row=lane&15, k=(lane>>4)*8+j ; B-frag: col=lane&15, same k.
// D-frag: col=lane&15, row=(lane>>4)*4+reg.
// ---------------------------------------------------------------------------
__device__ __forceinline__ void mfma_gemm(const u16* __restrict__ A,
                                          const u16* __restrict__ Wrow,
                                          f32x4 acc[8], int l)
{
    const int kg = l >> 4;
    const int ra = l & 15;
    #pragma unroll 2
    for (int ks = 0; ks < NSTATE; ks += 32) {
        const int kk = ks + kg * 8;
        bf16x8 b = *(const bf16x8*)(Wrow + kk);
        #pragma unroll
        for (int mf = 0; mf < 8; ++mf) {
            bf16x8 a = *(const bf16x8*)(A + (size_t)(mf * 16 + ra) * NSTATE + kk);
            acc[mf] = __builtin_amdgcn_mfma_f32_16x16x32_bf16(a, b, acc[mf], 0, 0, 0);
        }
    }
}

// q/k/v projection. grid (20, 3): y = mat. q -> ws (scaled+bias), k -> row 447
// of kout (no bias), v -> row 447 of vout (+bias).
__global__ void __launch_bounds__(256) proj_mfma_kernel(
    const u16* __restrict__ xbf, const u16* __restrict__ WT,
    const float* __restrict__ bq, const float* __restrict__ bv,
    float* __restrict__ q_ws, float* __restrict__ kout, float* __restrict__ vout)
{
    const int nt = blockIdx.x, z = blockIdx.y;
    const int w = threadIdx.x >> 6, l = threadIdx.x & 63;
    const int col = nt * 64 + w * 16 + (l & 15);
    const int kg = l >> 4;
    const u16* Wrow = WT + (size_t)z * NSTATE * NSTATE + (size_t)col * NSTATE;
    f32x4 acc[8] = {};
    mfma_gemm(xbf, Wrow, acc, l);

    const float bias = (z == 0) ? bq[col] : (z == 2) ? bv[col] : 0.f;
    #pragma unroll
    for (int mf = 0; mf < 8; ++mf) {
        #pragma unroll
        for (int j = 0; j < 4; ++j) {
            const int m = mf * 16 + kg * 4 + j;
            const float val = acc[mf][j] + bias;
            if (z == 0)      q_ws[(size_t)m * NSTATE + col] = val * 0.125f;
            else if (z == 1) kout[((size_t)m * TCACHE + TCACHE - 1) * NSTATE + col] = val;
            else             vout[((size_t)m * TCACHE + TCACHE - 1) * NSTATE + col] = val;
        }
    }
}

// output projection. grid (20).
__global__ void __launch_bounds__(256) outproj_mfma_kernel(
    const u16* __restrict__ wvbf, const u16* __restrict__ WT,
    const float* __restrict__ bo, float* __restrict__ out)
{
    const int nt = blockIdx.x;
    const int w = threadIdx.x >> 6, l = threadIdx.x & 63;
    const int col = nt * 64 + w * 16 + (l & 15);
    const int kg = l >> 4;
    const u16* Wrow = WT + (size_t)3 * NSTATE * NSTATE + (size_t)col * NSTATE;
    f32x4 acc[8] = {};
    mfma_gemm(wvbf, Wrow, acc, l);
    const float bias = bo[col];
    #pragma unroll
    for (int mf = 0; mf < 8; ++mf)
        #pragma unroll
        for (int j = 0; j < 4; ++j)
            out[(size_t)(mf * 16 + kg * 4 + j) * NSTATE + col] = acc[mf][j] + bias;
}

// ---------------------------------------------------------------------------
// K stream: contiguous nt row copy (shift) + all-head raw scores.
// ---------------------------------------------------------------------------
__global__ void __launch_bounds__(320) scorek_kernel(
    const float* __restrict__ kin, const float* __restrict__ q_ws,
    const float* __restrict__ mask, float* __restrict__ kout,
    float* __restrict__ sc_ws)
{
    const int tc = blockIdx.x, b = blockIdx.y;
    const int tid = threadIdx.x;
    const int h = tid >> 4;
    const int col = tid << 2;
    const size_t base = (size_t)b * TCACHE * NSTATE;
    const float4 q4 = *(const float4*)(q_ws + (size_t)b * NSTATE + col);
    const int t0 = tc * RPC;
    const int nrows = (tc == NT - 1) ? RPC - 1 : RPC;
    const float* src0 = kin + base + (size_t)(t0 + 1) * NSTATE + col;
    float* dst0 = kout + base + (size_t)t0 * NSTATE + col;
    float* scrow = sc_ws + ((size_t)b * NHEAD + h) * TCACHE + t0;

    #pragma unroll 4
    for (int r = 0; r < nrows; ++r) {
        f4 kv = __builtin_nontemporal_load((const f4*)(src0 + (size_t)r * NSTATE));
        __builtin_nontemporal_store(kv, (f4*)(dst0 + (size_t)r * NSTATE));
        float p = kv[0]*q4.x + kv[1]*q4.y + kv[2]*q4.z + kv[3]*q4.w;
        p += __shfl_xor(p, 1); p += __shfl_xor(p, 2);
        p += __shfl_xor(p, 4); p += __shfl_xor(p, 8);
        if ((tid & 15) == 0) scrow[r] = p + mask[t0 + r];
    }
    if (tc == NT - 1) {                       // row 447: already final in kout
        const f4 kv = *(const f4*)(kout + base + (size_t)(TCACHE-1) * NSTATE + col);
        float p = kv[0]*q4.x + kv[1]*q4.y + kv[2]*q4.z + kv[3]*q4.w;
        p += __shfl_xor(p, 1); p += __shfl_xor(p, 2);
        p += __shfl_xor(p, 4); p += __shfl_xor(p, 8);
        if ((tid & 15) == 0) scrow[RPC - 1] = p + mask[TCACHE - 1];
    }
}

// ---------------------------------------------------------------------------
// V stream: softmax stats on the fly + contiguous nt row copy + PV partials.
// ---------------------------------------------------------------------------
__global__ void __launch_bounds__(320) pvv_kernel(
    const float* __restrict__ vin, const float* __restrict__ sc_ws,
    float* __restrict__ vout, float* __restrict__ wvp)
{
    const int tc = blockIdx.x, b = blockIdx.y;
    const int tid = threadIdx.x;
    const int h = tid >> 4, l = tid & 15;
    const int col = tid << 2;
    const int t0 = tc * RPC;
    __shared__ float wl[NHEAD * RPC];

    const float* row = sc_ws + ((size_t)b * NHEAD + h) * TCACHE;
    float v[28];
    float m = -1e30f;
    #pragma unroll
    for (int j = 0; j < 28; ++j) { v[j] = row[l + 16*j]; m = fmaxf(m, v[j]); }
    #pragma unroll
    for (int d = 1; d <= 8; d <<= 1) m = fmaxf(m, __shfl_xor(m, d));
    float s = 0.f;
    #pragma unroll
    for (int j = 0; j < 28; ++j) s += __expf(v[j] - m);
    #pragma unroll
    for (int d = 1; d <= 8; d <<= 1) s += __shfl_xor(s, d);
    const float inv = 1.0f / s;
    #pragma unroll
    for (int j = 0; j < 4; ++j) {
        int r = l + 16*j;
        if (r < RPC) wl[h * RPC + r] = __expf(row[t0 + r] - m) * inv;
    }
    __syncthreads();

    const size_t base = (size_t)b * TCACHE * NSTATE;
    const int nrows = (tc == NT - 1) ? RPC - 1 : RPC;
    const float* src0 = vin + base + (size_t)(t0 + 1) * NSTATE + col;
    float* dst0 = vout + base + (size_t)t0 * NSTATE + col;
    float ax = 0.f, ay = 0.f, az = 0.f, aw = 0.f;
    #pragma unroll 4
    for (int r = 0; r < nrows; ++r) {
        f4 vv = __builtin_nontemporal_load((const f4*)(src0 + (size_t)r * NSTATE));
        __builtin_nontemporal_store(vv, (f4*)(dst0 + (size_t)r * NSTATE));
        const float w = wl[h * RPC + r];
        ax = fmaf(w, vv[0], ax); ay = fmaf(w, vv[1], ay);
        az = fmaf(w, vv[2], az); aw = fmaf(w, vv[3], aw);
    }
    if (tc == NT - 1) {
        const f4 vv = *(const f4*)(vout + base + (size_t)(TCACHE-1) * NSTATE + col);
        const float w = wl[h * RPC + RPC - 1];
        ax = fmaf(w, vv[0], ax); ay = fmaf(w, vv[1], ay);
        az = fmaf(w, vv[2], az); aw = fmaf(w, vv[3], aw);
    }
    *(float4*)(wvp + ((size_t)b * NT + tc) * NSTATE + col) =
        make_float4(ax, ay, az, aw);
}

// sum the NT chunk partials -> wv bf16 [128][1280]
__global__ void __launch_bounds__(256) wv_reduce_kernel(
    const float* __restrict__ wvp, u16* __restrict__ wvbf)
{
    const size_t idx = ((size_t)blockIdx.x * 256 + threadIdx.x) * 4;
    const int b = (int)(idx / NSTATE), col = (int)(idx % NSTATE);
    float4 s = make_float4(0.f, 0.f, 0.f, 0.f);
    #pragma unroll
    for (int c = 0; c < NT; ++c) {
        float4 a = *(const float4*)(wvp + ((size_t)b * NT + c) * NSTATE + col);
        s.x += a.x; s.y += a.y; s.z += a.z; s.w += a.w;
    }
    u16* o = wvbf + idx;
    o[0] = f2bf(s.x); o[1] = f2bf(s.y); o[2] = f2bf(s.z); o[3] = f2bf(s.w);
}

extern "C" void kernel_launch(void* const* d_in, const int* in_sizes, int n_in,
                              void* d_out, int out_size, void* d_ws, size_t ws_size,
                              hipStream_t stream)
{
    const float* x       = (const float*)d_in[0];
    const float* k_cache = (const float*)d_in[1];
    const float* v_cache = (const float*)d_in[2];
    const float* mask    = (const float*)d_in[3];
    const float* Wq      = (const float*)d_in[4];
    const float* bq      = (const float*)d_in[5];
    const float* Wk      = (const float*)d_in[6];
    const float* Wv      = (const float*)d_in[7];
    const float* bv      = (const float*)d_in[8];
    const float* Wo      = (const float*)d_in[9];
    const float* bo      = (const float*)d_in[10];

    float* out  = (float*)d_out;                                   // [128,1,1280]
    float* kout = out + (size_t)NBATCH * NSTATE;                   // [128,448,1280]
    float* vout = kout + (size_t)NBATCH * TCACHE * NSTATE;         // [128,448,1280]

    float* ws     = (float*)d_ws;
    float* q_ws   = ws;                                            // 163840 f
    float* sc_ws  = q_ws  + (size_t)NBATCH * NSTATE;               // 1146880 f
    float* wvp_ws = sc_ws + (size_t)NBATCH * NHEAD * TCACHE;       // 1310720 f
    u16*   WT     = (u16*)(wvp_ws + (size_t)NBATCH * NT * NSTATE); // 4*1280*1280 u16
    u16*   xbf    = WT + (size_t)4 * NSTATE * NSTATE;              // 163840 u16
    u16*   wvbf   = xbf + (size_t)NBATCH * NSTATE;                 // 163840 u16

    // 1) convert weights (transposed) + x to bf16
    cvt_kernel<<<dim3(20, 20, 5), 256, 0, stream>>>(Wq, Wk, Wv, Wo, x, WT, xbf);
    // 2) q/k/v projection (MFMA): q -> ws; k,v -> row 447 of output caches
    proj_mfma_kernel<<<dim3(20, 3), 256, 0, stream>>>(xbf, WT, bq, bv,
                                                      q_ws, kout, vout);
    // 3) K stream: shift-copy + raw scores
    scorek_kernel<<<dim3(NT, NBATCH), 320, 0, stream>>>(k_cache, q_ws, mask,
                                                        kout, sc_ws);
    // 4) V stream: softmax-on-the-fly + shift-copy + PV partials
    pvv_kernel<<<dim3(NT, NBATCH), 320, 0, stream>>>(v_cache, sc_ws, vout, wvp_ws);
    // 5) reduce partials -> wv (bf16)
    wv_reduce_kernel<<<dim3(160), 256, 0, stream>>>(wvp_ws, wvbf);
    // 6) output projection (MFMA) + bias
    outproj_mfma_kernel<<<dim3(20), 256, 0, stream>>>(wvbf, WT, bo, out);
}

// Round 5
// 308.442 us; speedup vs baseline: 1.1175x; 1.1175x over previous
//
#include <hip/hip_runtime.h>
#include <cstddef>

#define NSTATE 1280
#define TCACHE 448
#define NBATCH 128
#define NHEAD  20
#define HDIM   64
#define NT     8
#define RPC    (TCACHE / NT)   // 56 rows per chunk

typedef float f4 __attribute__((ext_vector_type(4)));

// ---------------------------------------------------------------------------
// fp32 tiled GEMM: C[m][n] = (A[128][1280] @ B[kb:ke][1280] + bias) * scale
// BM=64, BN=32, BK=32, 256 threads, micro-tile 4x2. ldc parameterized so k/v
// projections write directly into row 447 of the output caches.
// ---------------------------------------------------------------------------
__device__ __forceinline__ void gemm_body(const float* __restrict__ A,
                                          const float* __restrict__ B,
                                          const float* __restrict__ bias,
                                          float* __restrict__ C, size_t ldc,
                                          int kb, int ke, float scale)
{
    __shared__ float As[32][64];   // [k][m]
    __shared__ float Bs[32][32];   // [k][n]
    const int tid = threadIdx.x;
    const int m0 = blockIdx.y * 64;
    const int n0 = blockIdx.x * 32;
    const int tr = tid >> 4;
    const int tc = tid & 15;
    float acc[4][2] = {{0.f,0.f},{0.f,0.f},{0.f,0.f},{0.f,0.f}};

    for (int k0 = kb; k0 < ke; k0 += 32) {
        #pragma unroll
        for (int j = 0; j < 2; ++j) {
            int chunk = tid * 2 + j;
            int row   = chunk >> 3;
            int kc    = (chunk & 7) << 2;
            float4 a = *(const float4*)(A + (size_t)(m0 + row) * NSTATE + k0 + kc);
            As[kc+0][row] = a.x; As[kc+1][row] = a.y;
            As[kc+2][row] = a.z; As[kc+3][row] = a.w;
        }
        {
            int row = tid >> 3;
            int nc  = (tid & 7) << 2;
            float4 b4 = *(const float4*)(B + (size_t)(k0 + row) * NSTATE + n0 + nc);
            *(float4*)&Bs[row][nc] = b4;
        }
        __syncthreads();
        #pragma unroll
        for (int kk = 0; kk < 32; ++kk) {
            float4 a = *(const float4*)&As[kk][tr << 2];
            float2 b = *(const float2*)&Bs[kk][tc << 1];
            acc[0][0] = fmaf(a.x, b.x, acc[0][0]); acc[0][1] = fmaf(a.x, b.y, acc[0][1]);
            acc[1][0] = fmaf(a.y, b.x, acc[1][0]); acc[1][1] = fmaf(a.y, b.y, acc[1][1]);
            acc[2][0] = fmaf(a.z, b.x, acc[2][0]); acc[2][1] = fmaf(a.z, b.y, acc[2][1]);
            acc[3][0] = fmaf(a.w, b.x, acc[3][0]); acc[3][1] = fmaf(a.w, b.y, acc[3][1]);
        }
        __syncthreads();
    }
    const int n = n0 + (tc << 1);
    const float b0 = bias ? bias[n]   : 0.f;
    const float b1 = bias ? bias[n+1] : 0.f;
    #pragma unroll
    for (int i = 0; i < 4; ++i) {
        size_t m = (size_t)(m0 + (tr << 2) + i);
        C[m * ldc + n]     = (acc[i][0] + b0) * scale;
        C[m * ldc + n + 1] = (acc[i][1] + b1) * scale;
    }
}

// q/k/v projection, direct write. grid (40, 2, 3): z=0 q (scaled, ->ws),
// z=1 k -> row 447 kout (no bias), z=2 v -> row 447 vout.
__global__ void __launch_bounds__(256) proj_qkv_kernel(
    const float* __restrict__ x,
    const float* __restrict__ Wq, const float* __restrict__ bq,
    const float* __restrict__ Wk,
    const float* __restrict__ Wv, const float* __restrict__ bv,
    float* __restrict__ q_ws, float* __restrict__ kout, float* __restrict__ vout)
{
    const int z = blockIdx.z;
    if (z == 0) {
        gemm_body(x, Wq, bq, q_ws, NSTATE, 0, NSTATE, 0.125f);   // both scales folded
    } else if (z == 1) {
        gemm_body(x, Wk, nullptr, kout + (size_t)(TCACHE-1) * NSTATE,
                  (size_t)TCACHE * NSTATE, 0, NSTATE, 1.0f);
    } else {
        gemm_body(x, Wv, bv, vout + (size_t)(TCACHE-1) * NSTATE,
                  (size_t)TCACHE * NSTATE, 0, NSTATE, 1.0f);
    }
}

// ---------------------------------------------------------------------------
// Fused stream kernel: per (chunk, batch) block —
//   phase 1: shift-copy K rows + per-head scores into LDS
//   phase 2: chunk-local softmax (max m_c, sum s_c, weights)
//   phase 3: shift-copy V rows + PV partial with chunk-local weights
// Outputs: pv partial [b][tc][1280], m_c/s_c stats [b][tc][20].
// grid (NT, 128), 320 threads: thread = one float4 slot of a row, h = tid>>4.
// ---------------------------------------------------------------------------
__global__ void __launch_bounds__(320) fused_stream_kernel(
    const float* __restrict__ kin, const float* __restrict__ vin,
    const float* __restrict__ q_ws, const float* __restrict__ mask,
    float* __restrict__ kout, float* __restrict__ vout,
    float* __restrict__ pvp, float* __restrict__ m_ws, float* __restrict__ s_ws)
{
    const int tc = blockIdx.x, b = blockIdx.y;
    const int tid = threadIdx.x;
    const int h = tid >> 4, l = tid & 15;
    const int col = tid << 2;
    const size_t base = (size_t)b * TCACHE * NSTATE;
    const int t0 = tc * RPC;
    const int nrows = (tc == NT - 1) ? RPC - 1 : RPC;

    __shared__ float sc[NHEAD][RPC];   // raw scores, then weights

    const float4 q4 = *(const float4*)(q_ws + (size_t)b * NSTATE + col);

    // ---- phase 1: K shift-copy + scores ----
    {
        const float* src0 = kin + base + (size_t)(t0 + 1) * NSTATE + col;
        float* dst0 = kout + base + (size_t)t0 * NSTATE + col;
        #pragma unroll 4
        for (int r = 0; r < nrows; ++r) {
            f4 kv = __builtin_nontemporal_load((const f4*)(src0 + (size_t)r * NSTATE));
            __builtin_nontemporal_store(kv, (f4*)(dst0 + (size_t)r * NSTATE));
            float p = kv[0]*q4.x + kv[1]*q4.y + kv[2]*q4.z + kv[3]*q4.w;
            p += __shfl_xor(p, 1); p += __shfl_xor(p, 2);
            p += __shfl_xor(p, 4); p += __shfl_xor(p, 8);
            if (l == 0) sc[h][r] = p + mask[t0 + r];
        }
        if (tc == NT - 1) {            // row 447: already final in kout
            const f4 kv = *(const f4*)(kout + base + (size_t)(TCACHE-1) * NSTATE + col);
            float p = kv[0]*q4.x + kv[1]*q4.y + kv[2]*q4.z + kv[3]*q4.w;
            p += __shfl_xor(p, 1); p += __shfl_xor(p, 2);
            p += __shfl_xor(p, 4); p += __shfl_xor(p, 8);
            if (l == 0) sc[h][RPC - 1] = p + mask[TCACHE - 1];
        }
    }
    __syncthreads();

    // ---- phase 2: chunk-local softmax stats + weights ----
    {
        float v[4];
        float m = -1e30f;
        #pragma unroll
        for (int j = 0; j < 4; ++j) {
            int r = l + 16 * j;
            v[j] = (r < RPC) ? sc[h][r] : -1e30f;
            m = fmaxf(m, v[j]);
        }
        #pragma unroll
        for (int d = 1; d <= 8; d <<= 1) m = fmaxf(m, __shfl_xor(m, d));
        float s = 0.f;
        #pragma unroll
        for (int j = 0; j < 4; ++j) {
            v[j] = __expf(v[j] - m);   // exp(-1e30-m) -> 0 for pad slots
            s += v[j];
        }
        #pragma unroll
        for (int d = 1; d <= 8; d <<= 1) s += __shfl_xor(s, d);
        __syncthreads();               // all reads of sc done before overwrite
        #pragma unroll
        for (int j = 0; j < 4; ++j) {
            int r = l + 16 * j;
            if (r < RPC) sc[h][r] = v[j];
        }
        if (l == 0) {
            m_ws[((size_t)b * NT + tc) * NHEAD + h] = m;
            s_ws[((size_t)b * NT + tc) * NHEAD + h] = s;
        }
    }
    __syncthreads();

    // ---- phase 3: V shift-copy + PV partial (chunk-local weights) ----
    float ax = 0.f, ay = 0.f, az = 0.f, aw = 0.f;
    {
        const float* src0 = vin + base + (size_t)(t0 + 1) * NSTATE + col;
        float* dst0 = vout + base + (size_t)t0 * NSTATE + col;
        #pragma unroll 4
        for (int r = 0; r < nrows; ++r) {
            f4 vv = __builtin_nontemporal_load((const f4*)(src0 + (size_t)r * NSTATE));
            __builtin_nontemporal_store(vv, (f4*)(dst0 + (size_t)r * NSTATE));
            const float w = sc[h][r];
            ax = fmaf(w, vv[0], ax); ay = fmaf(w, vv[1], ay);
            az = fmaf(w, vv[2], az); aw = fmaf(w, vv[3], aw);
        }
        if (tc == NT - 1) {            // row 447: already final in vout
            const f4 vv = *(const f4*)(vout + base + (size_t)(TCACHE-1) * NSTATE + col);
            const float w = sc[h][RPC - 1];
            ax = fmaf(w, vv[0], ax); ay = fmaf(w, vv[1], ay);
            az = fmaf(w, vv[2], az); aw = fmaf(w, vv[3], aw);
        }
    }
    *(float4*)(pvp + ((size_t)b * NT + tc) * NSTATE + col) =
        make_float4(ax, ay, az, aw);
}

// ---------------------------------------------------------------------------
// Combine the NT chunk partials with online-softmax rescaling -> wv [128][1280]
// ---------------------------------------------------------------------------
__global__ void __launch_bounds__(256) combine_kernel(
    const float* __restrict__ pvp, const float* __restrict__ m_ws,
    const float* __restrict__ s_ws, float* __restrict__ wv_ws)
{
    const size_t idx = ((size_t)blockIdx.x * 256 + threadIdx.x) * 4;
    const int b = (int)(idx / NSTATE), col = (int)(idx % NSTATE);
    const int h = col >> 6;

    float m[NT], s[NT];
    float M = -1e30f;
    #pragma unroll
    for (int c = 0; c < NT; ++c) {
        m[c] = m_ws[((size_t)b * NT + c) * NHEAD + h];
        s[c] = s_ws[((size_t)b * NT + c) * NHEAD + h];
        M = fmaxf(M, m[c]);
    }
    float S = 0.f;
    float f[NT];
    #pragma unroll
    for (int c = 0; c < NT; ++c) { f[c] = __expf(m[c] - M); S += s[c] * f[c]; }
    const float inv = 1.0f / S;

    float4 acc = make_float4(0.f, 0.f, 0.f, 0.f);
    #pragma unroll
    for (int c = 0; c < NT; ++c) {
        const float w = f[c] * inv;
        float4 a = *(const float4*)(pvp + ((size_t)b * NT + c) * NSTATE + col);
        acc.x = fmaf(w, a.x, acc.x); acc.y = fmaf(w, a.y, acc.y);
        acc.z = fmaf(w, a.z, acc.z); acc.w = fmaf(w, a.w, acc.w);
    }
    *(float4*)(wv_ws + idx) = acc;
}

// output projection partials. grid (40, 2, 4): z = K-split (4 x 320).
__global__ void __launch_bounds__(256) outproj_kernel(
    const float* __restrict__ wv, const float* __restrict__ Wo,
    float* __restrict__ po)
{
    const int sp = blockIdx.z;
    gemm_body(wv, Wo, nullptr, po + (size_t)sp * NBATCH * NSTATE,
              NSTATE, sp * 320, sp * 320 + 320, 1.0f);
}

__global__ void __launch_bounds__(256) out_reduce_kernel(
    const float* __restrict__ po, const float* __restrict__ bo,
    float* __restrict__ out)
{
    const size_t idx = ((size_t)blockIdx.x * 256 + threadIdx.x) * 4;
    const int col = (int)(idx % NSTATE);
    float4 s = *(const float4*)(bo + col);
    #pragma unroll
    for (int c = 0; c < 4; ++c) {
        float4 a = *(const float4*)(po + (size_t)c * NBATCH * NSTATE + idx);
        s.x += a.x; s.y += a.y; s.z += a.z; s.w += a.w;
    }
    *(float4*)(out + idx) = s;
}

extern "C" void kernel_launch(void* const* d_in, const int* in_sizes, int n_in,
                              void* d_out, int out_size, void* d_ws, size_t ws_size,
                              hipStream_t stream)
{
    const float* x       = (const float*)d_in[0];
    const float* k_cache = (const float*)d_in[1];
    const float* v_cache = (const float*)d_in[2];
    const float* mask    = (const float*)d_in[3];
    const float* Wq      = (const float*)d_in[4];
    const float* bq      = (const float*)d_in[5];
    const float* Wk      = (const float*)d_in[6];
    const float* Wv      = (const float*)d_in[7];
    const float* bv      = (const float*)d_in[8];
    const float* Wo      = (const float*)d_in[9];
    const float* bo      = (const float*)d_in[10];

    float* out  = (float*)d_out;                                   // [128,1,1280]
    float* kout = out + (size_t)NBATCH * NSTATE;                   // [128,448,1280]
    float* vout = kout + (size_t)NBATCH * TCACHE * NSTATE;         // [128,448,1280]

    float* ws     = (float*)d_ws;
    float* q_ws   = ws;                                            // 163840
    float* pvp_ws = q_ws  + (size_t)NBATCH * NSTATE;               // 1310720
    float* m_ws   = pvp_ws + (size_t)NBATCH * NT * NSTATE;         // 20480
    float* s_ws   = m_ws  + (size_t)NBATCH * NT * NHEAD;           // 20480
    float* wv_ws  = s_ws  + (size_t)NBATCH * NT * NHEAD;           // 163840
    float* po_ws  = wv_ws + (size_t)NBATCH * NSTATE;               // 655360

    // 1) q/k/v projection: q -> ws (pre-scaled); k,v -> row 447 of out caches
    proj_qkv_kernel<<<dim3(40, 2, 3), 256, 0, stream>>>(x, Wq, bq, Wk, Wv, bv,
                                                        q_ws, kout, vout);
    // 2) fused K/V streams with chunk-local softmax
    fused_stream_kernel<<<dim3(NT, NBATCH), 320, 0, stream>>>(
        k_cache, v_cache, q_ws, mask, kout, vout, pvp_ws, m_ws, s_ws);
    // 3) combine chunk partials (online-softmax rescale)
    combine_kernel<<<dim3(160), 256, 0, stream>>>(pvp_ws, m_ws, s_ws, wv_ws);
    // 4) output projection (split-K) + reduce with bias
    outproj_kernel<<<dim3(40, 2, 4), 256, 0, stream>>>(wv_ws, Wo, po_ws);
    out_reduce_kernel<<<dim3(160), 256, 0, stream>>>(po_ws, bo, out);
}